// Round 7
// baseline (2727.487 us; speedup 1.0000x reference)
//
#include <hip/hip_runtime.h>
#include <hip/hip_bf16.h>
#include <math.h>

// Node classifier: KProp(K=2, gcn_norm) -> SAGEConv(64->64)+selu -> SAGEConv(64->40) -> softmax
// N=100000, E=1600000, D=H=64, C=40. All fp32.
//
// R7 structure: chunk-aligned gather props for per-XCD L2 reuse.
//   Edges sorted by (strip = dst>>5, chunk = src>>13). One wave per strip (32 dst
//   nodes), fp32 accumulator strip in LDS via ds_add_f32; linear edge traversal is
//   chunk-major, so all co-resident waves sweep the same 2MB src window together.
//   CSR build: partition into 98 coarse dst-buckets (block-private segments, packed
//   u32), then per-bucket counting sort by (strip,chunk) + deg/dis/cnt_inv.
//   Pipeline (linearity reorder): p0=Sx; h=Sp0; [t1|r1]=h@[Wl1|Wr1];
//   h1=selu(mean(t1)+r1+b1); [t2|r2+b2]=h1@[Wl2|Wr2]; out=softmax(mean(t2)+r2).

#define RFL(x) __builtin_amdgcn_readfirstlane(x)
#define BK_SHIFT 10        // coarse bucket = dst>>10 (1024 nodes)
#define STRIP_SHIFT 5      // strip = dst>>5 (32 nodes per wave)
#define CH_SHIFT 13        // src chunk = src>>13 (8192 nodes = 2MB @64 floats)
#define NCHUNK 13          // ceil(100000/8192)
#define MAXBUCK 256

// ---------------- CSR build ----------------

__global__ void init_bcursor_kernel(int* __restrict__ bcursor, int nbuck, int cap) {
    int i = blockIdx.x * blockDim.x + threadIdx.x;
    if (i < nbuck) bcursor[i] = i * cap;
}

// Phase 1: block-private coarse bucket partition; packed u32 entries.
__global__ __launch_bounds__(256) void partition_kernel(const int* __restrict__ src,
                                                        const int* __restrict__ dst,
                                                        int* __restrict__ bcursor,
                                                        unsigned int* __restrict__ temp,
                                                        int e, int nbuck, int cap) {
    __shared__ int bc[MAXBUCK];
    int t = threadIdx.x;
    int chunk = (e + gridDim.x - 1) / gridDim.x;
    int base = blockIdx.x * chunk;
    int cnt = e - base;
    if (cnt > chunk) cnt = chunk;
    if (cnt < 0) cnt = 0;
    for (int j = t; j < nbuck; j += 256) bc[j] = 0;
    __syncthreads();
    for (int i = t; i < cnt; i += 256) {
        int d = dst[base + i];
        atomicAdd(&bc[d >> BK_SHIFT], 1);
    }
    __syncthreads();
    for (int j = t; j < nbuck; j += 256) {
        int c = bc[j];
        bc[j] = (c > 0) ? atomicAdd(&bcursor[j], c) : 0;
    }
    __syncthreads();
    for (int i = t; i < cnt; i += 256) {
        int s = src[base + i];
        int d = dst[base + i];
        int bk = d >> BK_SHIFT;
        int p = atomicAdd(&bc[bk], 1);
        if (p < (bk + 1) * cap) temp[p] = ((unsigned int)s << BK_SHIFT) | (unsigned int)(d & 1023);
    }
}

// Phase 2: per-bucket counting sort by (strip_local, chunk) + node stats.
// One WG (256 thr) per bucket of 1024 nodes = 32 strips.
__global__ __launch_bounds__(256) void bucket_csr_kernel(const unsigned int* __restrict__ temp,
                                                         const int* __restrict__ bcursor,
                                                         float* __restrict__ dis,
                                                         float* __restrict__ cnt_inv,
                                                         unsigned int* __restrict__ csr,
                                                         int* __restrict__ strip_off,
                                                         int n, int cap, int nbuck, int e,
                                                         int nstrips) {
    __shared__ int sdeg[1024];
    __shared__ int cnt2[32 * NCHUNK];
    __shared__ int part[256];
    __shared__ int stot[32];
    int b = blockIdx.x;
    int t = threadIdx.x;
    int nbeg = b << BK_SHIFT;
    // bbase = exclusive prefix of bucket counts
    int cj = 0;
    if (t < nbuck) {
        cj = bcursor[t] - t * cap;
        if (cj > cap) cj = cap;
    }
    part[t] = cj;
    __syncthreads();
    for (int off = 1; off < 256; off <<= 1) {
        int u = (t >= off) ? part[t - off] : 0;
        __syncthreads();
        part[t] += u;
        __syncthreads();
    }
    int cntb = bcursor[b] - b * cap;
    if (cntb > cap) cntb = cap;
    int bbase = part[b] - cntb;
    __syncthreads();
    // zero counters
    for (int i = t; i < 1024; i += 256) sdeg[i] = 0;
    for (int i = t; i < 32 * NCHUNK; i += 256) cnt2[i] = 0;
    __syncthreads();
    const unsigned int* tb = temp + (size_t)b * cap;
    for (int i = t; i < cntb; i += 256) {
        unsigned int ed = tb[i];
        int dstloc = ed & 1023;
        int s = ed >> BK_SHIFT;
        atomicAdd(&sdeg[dstloc], 1);
        atomicAdd(&cnt2[(dstloc >> STRIP_SHIFT) * NCHUNK + (s >> CH_SHIFT)], 1);
    }
    __syncthreads();
    // node stats (4 nodes per thread)
#pragma unroll
    for (int k = 0; k < 4; ++k) {
        int idx = t * 4 + k;
        int node = nbeg + idx;
        if (node < n) {
            int d = sdeg[idx];
            float fd = (float)d;
            dis[node] = (d > 0) ? rsqrtf(fd) : 0.0f;
            cnt_inv[node] = 1.0f / fmaxf(fd, 1.0f);
        }
    }
    // strip totals + per-strip chunk offsets
    if (t < 32) {
        int run = 0;
        for (int c = 0; c < NCHUNK; ++c) run += cnt2[t * NCHUNK + c];
        stot[t] = run;
    }
    __syncthreads();
    if (t == 0) {
        int run = 0;
        for (int sl = 0; sl < 32; ++sl) {
            int v = stot[sl];
            stot[sl] = run;
            run += v;
        }
    }
    __syncthreads();
    if (t < 32) {
        int run = stot[t];   // strip-exclusive base within bucket
        int gs = b * 32 + t;
        if (gs < nstrips) strip_off[gs] = bbase + run;
        for (int c = 0; c < NCHUNK; ++c) {
            int v = cnt2[t * NCHUNK + c];
            cnt2[t * NCHUNK + c] = run;
            run += v;
        }
    }
    if (b == nbuck - 1 && t == 0) strip_off[nstrips] = bbase + cntb;
    __syncthreads();
    // scatter: packed (src<<5 | node_local)
    for (int i = t; i < cntb; i += 256) {
        unsigned int ed = tb[i];
        int dstloc = ed & 1023;
        int s = ed >> BK_SHIFT;
        int pos = atomicAdd(&cnt2[(dstloc >> STRIP_SHIFT) * NCHUNK + (s >> CH_SHIFT)], 1);
        csr[bbase + pos] = ((unsigned int)s << STRIP_SHIFT) | (unsigned int)(dstloc & 31);
    }
}

// ---------------- chunk-aligned propagation ----------------
// One wave per strip of 32 dst nodes; acc[32][64] fp32 in LDS (8KB/wave).
// FW: input row width (64 or 40). USE_W: weight=dis[src].
// EPI: 0 = out*sc ; 1 = selu(acc*sc + r + bias) ; 2 = softmax(acc*sc + r), 40 cols.
template <int FW, bool USE_W, int EPI>
__global__ __launch_bounds__(256) void propc_kernel(const float* __restrict__ in,
                                                    float* __restrict__ out,
                                                    const int* __restrict__ strip_off,
                                                    const unsigned int* __restrict__ csr,
                                                    const float* __restrict__ dis,
                                                    const float* __restrict__ nscale,
                                                    const float* __restrict__ r_add,
                                                    const float* __restrict__ bias,
                                                    int n, int nstrips) {
    __shared__ float acc[4 * 32 * 64];
    int wid = threadIdx.x >> 6;
    int lane = threadIdx.x & 63;
    int strip = RFL(blockIdx.x * 4 + wid);
    if (strip >= nstrips) return;
    float* accw = acc + wid * 2048;
    for (int i = lane; i < 2048; i += 64) accw[i] = 0.0f;
    int beg = RFL(strip_off[strip]);
    int end = RFL(strip_off[strip + 1]);
    const bool act = (FW == 64) || (lane < FW);
    int j = beg;
    for (; j + 8 <= end; j += 8) {
        unsigned int e[8];
#pragma unroll
        for (int q = 0; q < 8; ++q) e[q] = csr[j + q];
        float v[8];
        float w[8];
#pragma unroll
        for (int q = 0; q < 8; ++q) {
            int s = e[q] >> STRIP_SHIFT;
            v[q] = act ? in[(size_t)s * FW + lane] : 0.0f;
            w[q] = USE_W ? dis[s] : 1.0f;
        }
#pragma unroll
        for (int q = 0; q < 8; ++q) {
            int nl = e[q] & 31;
            if (act) atomicAdd(&accw[nl * 64 + lane], w[q] * v[q]);
        }
    }
    for (; j < end; ++j) {
        unsigned int eq = csr[j];
        int s = eq >> STRIP_SHIFT;
        int nl = eq & 31;
        float w = USE_W ? dis[s] : 1.0f;
        if (act) {
            float v = in[(size_t)s * FW + lane];
            atomicAdd(&accw[nl * 64 + lane], w * v);
        }
    }
    // epilogue
    int n0 = strip << STRIP_SHIFT;
    if (EPI == 0) {
        for (int nl = 0; nl < 32; ++nl) {
            int node = n0 + nl;
            if (node >= n) break;
            float sc = nscale[node];
            out[(size_t)node * 64 + lane] = accw[nl * 64 + lane] * sc;
        }
    } else if (EPI == 1) {
        float bb = bias[lane];
        const float scale = 1.0507009873554805f;
        const float alpha = 1.6732632423543772f;
        for (int nl = 0; nl < 32; ++nl) {
            int node = n0 + nl;
            if (node >= n) break;
            float sc = nscale[node];
            float tt = accw[nl * 64 + lane] * sc + r_add[(size_t)node * 64 + lane] + bb;
            tt = scale * (tt > 0.0f ? tt : alpha * expm1f(tt));
            out[(size_t)node * 64 + lane] = tt;
        }
    } else {
        for (int nl = 0; nl < 32; ++nl) {
            int node = n0 + nl;
            if (node >= n) break;
            float sc = nscale[node];
            float tt = 0.0f;
            if (lane < 40) tt = accw[nl * 64 + lane] * sc + r_add[(size_t)node * 40 + lane];
            float x = (lane < 40) ? tt : -INFINITY;
            float m = x;
            for (int off = 32; off; off >>= 1) m = fmaxf(m, __shfl_xor(m, off));
            float ex = (lane < 40) ? __expf(x - m) : 0.0f;
            float ss = ex;
            for (int off = 32; off; off >>= 1) ss += __shfl_xor(ss, off);
            if (lane < 40) out[(size_t)node * 40 + lane] = ex / ss;
        }
    }
}

// ---------------- tiled GEMM: [outL|outR] = in(64) @ [Wl|Wr] ----------------
template <int OC, int CP>
__global__ __launch_bounds__(256) void gemm_kernel(const float* __restrict__ in,
                                                   const float* __restrict__ Wl,
                                                   const float* __restrict__ Wr,
                                                   const float* __restrict__ bias,
                                                   float* __restrict__ outL,
                                                   float* __restrict__ outR,
                                                   int n, int add_bias) {
    constexpr int HC = OC / 2;
    constexpr int TX = OC / CP;
    constexpr int TY = 256 / TX;
    constexpr int NPT = 64 / TY;
    constexpr int XP = 68;
    constexpr int WP = OC + 4;
    __shared__ float sXT[64 * XP];
    __shared__ float sW[64 * WP];
    int t = threadIdx.x;
    int blk = blockIdx.x;
    for (int i = 0; i < 16; ++i) {
        int idx = i * 256 + t;
        int nd = idx >> 6;
        int k = idx & 63;
        int ng = blk * 64 + nd;
        float v = in[(size_t)(ng < n ? ng : n - 1) * 64 + k];
        sXT[k * XP + nd] = v;
    }
    for (int i = t; i < 64 * HC; i += 256) {
        int k = i / HC;
        int c = i % HC;
        sW[k * WP + c] = Wl[i];
        sW[k * WP + HC + c] = Wr[i];
    }
    __syncthreads();
    int tx = t % TX;
    int ty = t / TX;
    float acc[NPT][CP];
#pragma unroll
    for (int i = 0; i < NPT; ++i)
#pragma unroll
        for (int c = 0; c < CP; ++c) acc[i][c] = 0.0f;
#pragma unroll 4
    for (int k = 0; k < 64; ++k) {
        float xv[NPT];
#pragma unroll
        for (int i = 0; i < NPT; ++i) xv[i] = sXT[k * XP + ty * NPT + i];
        float wv[CP];
#pragma unroll
        for (int c = 0; c < CP; ++c) wv[c] = sW[k * WP + tx * CP + c];
#pragma unroll
        for (int i = 0; i < NPT; ++i)
#pragma unroll
            for (int c = 0; c < CP; ++c) acc[i][c] += xv[i] * wv[c];
    }
#pragma unroll
    for (int i = 0; i < NPT; ++i) {
        int ng = blk * 64 + ty * NPT + i;
        if (ng >= n) break;
#pragma unroll
        for (int c = 0; c < CP; ++c) {
            int col = tx * CP + c;
            if (col < HC) {
                outL[(size_t)ng * HC + col] = acc[i][c];
            } else {
                float v = acc[i][c] + (add_bias ? bias[col - HC] : 0.0f);
                outR[(size_t)ng * HC + (col - HC)] = v;
            }
        }
    }
}

// ---------------- launch ----------------

extern "C" void kernel_launch(void* const* d_in, const int* in_sizes, int n_in,
                              void* d_out, int out_size, void* d_ws, size_t ws_size,
                              hipStream_t stream) {
    const float* x   = (const float*)d_in[0];
    const float* Wl1 = (const float*)d_in[1];
    const float* Wr1 = (const float*)d_in[2];
    const float* b1  = (const float*)d_in[3];
    const float* Wl2 = (const float*)d_in[4];
    const float* Wr2 = (const float*)d_in[5];
    const float* b2  = (const float*)d_in[6];
    const int* edge_src = (const int*)d_in[7];
    const int* edge_dst = (const int*)d_in[8];
    float* out = (float*)d_out;

    const int N = in_sizes[0] / 64;
    const int E = in_sizes[7];
    const int NBUCK = (N + (1 << BK_SHIFT) - 1) >> BK_SHIFT;      // 98
    const int NSTRIPS = (N + 31) >> STRIP_SHIFT;                  // 3125
    size_t bufC_bytes = (size_t)N * 64 * 4;
    int cap = E / NBUCK + E / (2 * NBUCK) + 1024;                 // mean + 50% + slack
    int cap_max = (int)(bufC_bytes / ((size_t)NBUCK * 4));        // u32 temp entries
    if (cap > cap_max) cap = cap_max;

    size_t off = 0;
    auto carve = [&](size_t bytes) -> void* {
        void* p = (char*)d_ws + off;
        off = (off + bytes + 255) & ~(size_t)255;
        return p;
    };
    int*          strip_off = (int*)carve((size_t)(NSTRIPS + 1) * 4);
    int*          bcursor   = (int*)carve((size_t)NBUCK * 4);
    float*        dis       = (float*)carve((size_t)N * 4);
    float*        cnt_inv   = (float*)carve((size_t)N * 4);
    unsigned int* csr       = (unsigned int*)carve((size_t)E * 4);
    float*        bufA      = (float*)carve((size_t)N * 64 * 4);
    float*        bufB      = (float*)carve((size_t)N * 64 * 4);
    float*        bufC      = (float*)carve(bufC_bytes);
    unsigned int* temp      = (unsigned int*)bufC;   // alias: dead before bufC written
    (void)ws_size;

    const int nb_prop = (NSTRIPS + 3) / 4;    // 4 waves (strips) per block
    const int nb_gemm = (N + 63) / 64;

    // CSR build
    init_bcursor_kernel<<<(NBUCK + 255) / 256, 256, 0, stream>>>(bcursor, NBUCK, cap);
    partition_kernel<<<256, 256, 0, stream>>>(edge_src, edge_dst, bcursor, temp, E, NBUCK, cap);
    bucket_csr_kernel<<<NBUCK, 256, 0, stream>>>(temp, bcursor, dis, cnt_inv, csr, strip_off,
                                                 N, cap, NBUCK, E, NSTRIPS);

    // KProp x2: h = S (S x)
    propc_kernel<64, true, 0><<<nb_prop, 256, 0, stream>>>(x, bufA, strip_off, csr, dis, dis,
                                                           nullptr, nullptr, N, NSTRIPS);
    propc_kernel<64, true, 0><<<nb_prop, 256, 0, stream>>>(bufA, bufB, strip_off, csr, dis, dis,
                                                           nullptr, nullptr, N, NSTRIPS);
    // [t1|r1] = h @ [Wl1|Wr1]  (t1 -> bufA, r1 -> bufC)
    gemm_kernel<128, 8><<<nb_gemm, 256, 0, stream>>>(bufB, Wl1, Wr1, nullptr, bufA, bufC, N, 0);
    // h1 = selu(mean_agg(t1) + r1 + b1) -> bufB
    propc_kernel<64, false, 1><<<nb_prop, 256, 0, stream>>>(bufA, bufB, strip_off, csr, dis,
                                                            cnt_inv, bufC, b1, N, NSTRIPS);
    // [t2|r2+b2] = h1 @ [Wl2|Wr2]  (t2 -> bufA (N x 40), r2 -> bufC (N x 40))
    gemm_kernel<80, 5><<<nb_gemm, 256, 0, stream>>>(bufB, Wl2, Wr2, b2, bufA, bufC, N, 1);
    // out = softmax(mean_agg(t2) + r2)
    propc_kernel<40, false, 2><<<nb_prop, 256, 0, stream>>>(bufA, out, strip_off, csr, dis,
                                                            cnt_inv, bufC, nullptr, N, NSTRIPS);
}

// Round 8
// 548.206 us; speedup vs baseline: 4.9753x; 4.9753x over previous
//
#include <hip/hip_runtime.h>
#include <hip/hip_bf16.h>
#include <math.h>

// Node classifier: KProp(K=2, gcn_norm) -> SAGEConv(64->64)+selu -> SAGEConv(64->40) -> softmax
// N=100000, E=1600000, D=H=64, C=40. All fp32.
//
// R8: chunk-aligned props (validated by R7's FETCH drop) with a fixed engine:
//   - strip = 16 dst nodes/wave (16KB LDS/block -> ~6 blocks/CU, 24 waves/CU)
//   - edges sorted by (strip, chunk=src>>13, node): register-accumulated runs,
//     ONE plain LDS read-add-write per run (no atomics, wave-private acc slice)
//   - bucket_csr: counting sort over 64x13x16 LDS counters; deg derived from counts
//   - distinct TAG per prop dispatch for profile visibility

#define RFL(x) __builtin_amdgcn_readfirstlane(x)
#define BK_SHIFT 10        // coarse bucket = dst>>10 (1024 nodes)
#define SSHIFT 4           // strip = 16 nodes per wave
#define CH_SHIFT 13        // src chunk = src>>13 (8192 rows = 2MB @ 64 floats)
#define NCHUNK 13          // ceil(100000/8192)
#define SPB 64             // strips per bucket = 1024/16
#define KPB (SPB * NCHUNK * 16)   // 13312 sort keys per bucket
#define MAXBUCK 256

// ---------------- CSR build ----------------

__global__ void init_bcursor_kernel(int* __restrict__ bcursor, int nbuck, int cap) {
    int i = blockIdx.x * blockDim.x + threadIdx.x;
    if (i < nbuck) bcursor[i] = i * cap;
}

// Phase 1: block-private coarse bucket partition; packed u32 (src<<10 | dst&1023).
__global__ __launch_bounds__(256) void partition_kernel(const int* __restrict__ src,
                                                        const int* __restrict__ dst,
                                                        int* __restrict__ bcursor,
                                                        unsigned int* __restrict__ temp,
                                                        int e, int nbuck, int cap) {
    __shared__ int bc[MAXBUCK];
    int t = threadIdx.x;
    int chunk = (e + gridDim.x - 1) / gridDim.x;
    int base = blockIdx.x * chunk;
    int cnt = e - base;
    if (cnt > chunk) cnt = chunk;
    if (cnt < 0) cnt = 0;
    for (int j = t; j < nbuck; j += 256) bc[j] = 0;
    __syncthreads();
    for (int i = t; i < cnt; i += 256) {
        int d = dst[base + i];
        atomicAdd(&bc[d >> BK_SHIFT], 1);
    }
    __syncthreads();
    for (int j = t; j < nbuck; j += 256) {
        int c = bc[j];
        bc[j] = (c > 0) ? atomicAdd(&bcursor[j], c) : 0;
    }
    __syncthreads();
    for (int i = t; i < cnt; i += 256) {
        int s = src[base + i];
        int d = dst[base + i];
        int bk = d >> BK_SHIFT;
        int p = atomicAdd(&bc[bk], 1);
        if (p < (bk + 1) * cap) temp[p] = ((unsigned int)s << BK_SHIFT) | (unsigned int)(d & 1023);
    }
}

// Phase 2: per-bucket counting sort by (strip_local, chunk, node_local) + stats.
// One WG (256 thr) per bucket of 1024 nodes = 64 strips of 16.
__global__ __launch_bounds__(256) void bucket_csr_kernel(const unsigned int* __restrict__ temp,
                                                         const int* __restrict__ bcursor,
                                                         float* __restrict__ dis,
                                                         float* __restrict__ cnt_inv,
                                                         unsigned int* __restrict__ csr,
                                                         int* __restrict__ strip_off,
                                                         int n, int cap, int nbuck, int e,
                                                         int nstrips) {
    __shared__ int cnt3[KPB];      // 53KB: counts, then exclusive prefix, then cursors
    __shared__ int part[256];
    int b = blockIdx.x;
    int t = threadIdx.x;
    int nbeg = b << BK_SHIFT;
    // ---- bbase = exclusive prefix of bucket counts ----
    int cj = 0;
    if (t < nbuck) {
        cj = bcursor[t] - t * cap;
        if (cj > cap) cj = cap;
    }
    part[t] = cj;
    __syncthreads();
    for (int off = 1; off < 256; off <<= 1) {
        int u = (t >= off) ? part[t - off] : 0;
        __syncthreads();
        part[t] += u;
        __syncthreads();
    }
    int cntb = bcursor[b] - b * cap;
    if (cntb > cap) cntb = cap;
    int bbase = part[b] - cntb;
    __syncthreads();
    // ---- zero counters ----
    for (int i = t; i < KPB; i += 256) cnt3[i] = 0;
    __syncthreads();
    // ---- count by (strip_local, chunk, node_local) ----
    const unsigned int* tb = temp + (size_t)b * cap;
    for (int i = t; i < cntb; i += 256) {
        unsigned int ed = tb[i];
        int dstloc = (int)(ed & 1023u);
        int s = (int)(ed >> BK_SHIFT);
        int key = ((dstloc >> SSHIFT) * NCHUNK + (s >> CH_SHIFT)) * 16 + (dstloc & 15);
        atomicAdd(&cnt3[key], 1);
    }
    __syncthreads();
    // ---- per-node degree from counts (before prefix overwrites) ----
#pragma unroll
    for (int k = 0; k < 4; ++k) {
        int idx = t * 4 + k;             // node-local 0..1023
        int sl = idx >> SSHIFT;
        int nl = idx & 15;
        int d = 0;
        for (int c = 0; c < NCHUNK; ++c) d += cnt3[(sl * NCHUNK + c) * 16 + nl];
        int node = nbeg + idx;
        if (node < n) {
            float fd = (float)d;
            dis[node] = (d > 0) ? rsqrtf(fd) : 0.0f;
            cnt_inv[node] = 1.0f / fmaxf(fd, 1.0f);
        }
    }
    // ---- block-wide exclusive prefix over cnt3 (13312 entries) ----
    const int PER = (KPB + 255) / 256;   // 52
    int my0 = t * PER;
    int run = 0;
    for (int i = 0; i < PER; ++i) {
        int idx = my0 + i;
        if (idx < KPB) run += cnt3[idx];
    }
    __syncthreads();                      // all reads of counts done
    part[t] = run;
    __syncthreads();
    for (int off = 1; off < 256; off <<= 1) {
        int u = (t >= off) ? part[t - off] : 0;
        __syncthreads();
        part[t] += u;
        __syncthreads();
    }
    int accp = part[t] - run;             // exclusive
    for (int i = 0; i < PER; ++i) {
        int idx = my0 + i;
        if (idx < KPB) {
            int v = cnt3[idx];
            cnt3[idx] = accp;
            accp += v;
        }
    }
    __syncthreads();
    // ---- strip offsets ----
    if (t < SPB) {
        int gs = b * SPB + t;
        if (gs < nstrips) strip_off[gs] = bbase + cnt3[(t * NCHUNK + 0) * 16 + 0];
    }
    if (b == nbuck - 1 && t == 0) strip_off[nstrips] = bbase + cntb;
    __syncthreads();
    // ---- scatter: packed (src<<4 | node_local) ----
    for (int i = t; i < cntb; i += 256) {
        unsigned int ed = tb[i];
        int dstloc = (int)(ed & 1023u);
        int s = (int)(ed >> BK_SHIFT);
        int key = ((dstloc >> SSHIFT) * NCHUNK + (s >> CH_SHIFT)) * 16 + (dstloc & 15);
        int pos = atomicAdd(&cnt3[key], 1);
        csr[bbase + pos] = ((unsigned int)s << SSHIFT) | (unsigned int)(dstloc & 15);
    }
}

// ---------------- chunk-aligned propagation (strip = 16 nodes / wave) ----------------
// Edges sorted by (strip, chunk, node): register-accumulate equal-node runs, one
// plain LDS RMW per run. FW: input row width. USE_W: weight = dis[src].
// EPI: 0 = out*sc ; 1 = selu(acc*sc + r + bias) ; 2 = softmax(acc*sc + r), 40 cols.
template <int FW, bool USE_W, int EPI, int TAG>
__global__ __launch_bounds__(256) void propc2_kernel(const float* __restrict__ in,
                                                     float* __restrict__ out,
                                                     const int* __restrict__ strip_off,
                                                     const unsigned int* __restrict__ csr,
                                                     const float* __restrict__ dis,
                                                     const float* __restrict__ nscale,
                                                     const float* __restrict__ r_add,
                                                     const float* __restrict__ bias,
                                                     int n, int nstrips) {
    __shared__ float accs[4][16 * 64];
    int wid = threadIdx.x >> 6;
    int lane = threadIdx.x & 63;
    int strip = RFL((int)blockIdx.x * 4 + wid);
    if (strip >= nstrips) return;
    float* accw = accs[wid];
#pragma unroll
    for (int i = 0; i < 16; ++i) accw[i * 64 + lane] = 0.0f;
    int beg = RFL(strip_off[strip]);
    int end = RFL(strip_off[strip + 1]);
    const bool act = (FW == 64) || (lane < FW);
    float rsum = 0.0f;
    int cur = -1;
    int j = beg;
    for (; j + 8 <= end; j += 8) {
        unsigned int e[8];
#pragma unroll
        for (int q = 0; q < 8; ++q) e[q] = csr[j + q];
        float v[8], w[8];
#pragma unroll
        for (int q = 0; q < 8; ++q) {
            int s = (int)(e[q] >> SSHIFT);
            v[q] = act ? in[(size_t)s * FW + lane] : 0.0f;
            w[q] = USE_W ? dis[s] : 1.0f;
        }
#pragma unroll
        for (int q = 0; q < 8; ++q) {
            int nl = (int)(e[q] & 15u);
            if (nl != cur) {                       // wave-uniform branch
                if (cur >= 0) accw[cur * 64 + lane] += rsum;
                cur = nl;
                rsum = 0.0f;
            }
            rsum += w[q] * v[q];
        }
    }
    for (; j < end; ++j) {
        unsigned int eq = csr[j];
        int s = (int)(eq >> SSHIFT);
        int nl = (int)(eq & 15u);
        float v = act ? in[(size_t)s * FW + lane] : 0.0f;
        float w = USE_W ? dis[s] : 1.0f;
        if (nl != cur) {
            if (cur >= 0) accw[cur * 64 + lane] += rsum;
            cur = nl;
            rsum = 0.0f;
        }
        rsum += w * v;
    }
    if (cur >= 0) accw[cur * 64 + lane] += rsum;
    // ---- epilogue ----
    int n0 = strip << SSHIFT;
    if (EPI == 0) {
#pragma unroll 4
        for (int nl = 0; nl < 16; ++nl) {
            int node = n0 + nl;
            if (node >= n) break;
            float sc = nscale[node];
            out[(size_t)node * 64 + lane] = accw[nl * 64 + lane] * sc;
        }
    } else if (EPI == 1) {
        float bb = bias[lane];
        const float scale = 1.0507009873554805f;
        const float alpha = 1.6732632423543772f;
#pragma unroll 4
        for (int nl = 0; nl < 16; ++nl) {
            int node = n0 + nl;
            if (node >= n) break;
            float sc = nscale[node];
            float tt = accw[nl * 64 + lane] * sc + r_add[(size_t)node * 64 + lane] + bb;
            tt = scale * (tt > 0.0f ? tt : alpha * expm1f(tt));
            out[(size_t)node * 64 + lane] = tt;
        }
    } else {
        for (int nl = 0; nl < 16; ++nl) {
            int node = n0 + nl;
            if (node >= n) break;
            float sc = nscale[node];
            float tt = 0.0f;
            if (lane < 40) tt = accw[nl * 64 + lane] * sc + r_add[(size_t)node * 40 + lane];
            float x = (lane < 40) ? tt : -INFINITY;
            float m = x;
            for (int off = 32; off; off >>= 1) m = fmaxf(m, __shfl_xor(m, off));
            float ex = (lane < 40) ? __expf(x - m) : 0.0f;
            float ss = ex;
            for (int off = 32; off; off >>= 1) ss += __shfl_xor(ss, off);
            if (lane < 40) out[(size_t)node * 40 + lane] = ex / ss;
        }
    }
}

// ---------------- tiled GEMM: [outL|outR] = in(64) @ [Wl|Wr] ----------------
template <int OC, int CP>
__global__ __launch_bounds__(256) void gemm_kernel(const float* __restrict__ in,
                                                   const float* __restrict__ Wl,
                                                   const float* __restrict__ Wr,
                                                   const float* __restrict__ bias,
                                                   float* __restrict__ outL,
                                                   float* __restrict__ outR,
                                                   int n, int add_bias) {
    constexpr int HC = OC / 2;
    constexpr int TX = OC / CP;
    constexpr int TY = 256 / TX;
    constexpr int NPT = 64 / TY;
    constexpr int XP = 68;
    constexpr int WP = OC + 4;
    __shared__ float sXT[64 * XP];
    __shared__ float sW[64 * WP];
    int t = threadIdx.x;
    int blk = blockIdx.x;
    for (int i = 0; i < 16; ++i) {
        int idx = i * 256 + t;
        int nd = idx >> 6;
        int k = idx & 63;
        int ng = blk * 64 + nd;
        float v = in[(size_t)(ng < n ? ng : n - 1) * 64 + k];
        sXT[k * XP + nd] = v;
    }
    for (int i = t; i < 64 * HC; i += 256) {
        int k = i / HC;
        int c = i % HC;
        sW[k * WP + c] = Wl[i];
        sW[k * WP + HC + c] = Wr[i];
    }
    __syncthreads();
    int tx = t % TX;
    int ty = t / TX;
    float acc[NPT][CP];
#pragma unroll
    for (int i = 0; i < NPT; ++i)
#pragma unroll
        for (int c = 0; c < CP; ++c) acc[i][c] = 0.0f;
#pragma unroll 4
    for (int k = 0; k < 64; ++k) {
        float xv[NPT];
#pragma unroll
        for (int i = 0; i < NPT; ++i) xv[i] = sXT[k * XP + ty * NPT + i];
        float wv[CP];
#pragma unroll
        for (int c = 0; c < CP; ++c) wv[c] = sW[k * WP + tx * CP + c];
#pragma unroll
        for (int i = 0; i < NPT; ++i)
#pragma unroll
            for (int c = 0; c < CP; ++c) acc[i][c] += xv[i] * wv[c];
    }
#pragma unroll
    for (int i = 0; i < NPT; ++i) {
        int ng = blk * 64 + ty * NPT + i;
        if (ng >= n) break;
#pragma unroll
        for (int c = 0; c < CP; ++c) {
            int col = tx * CP + c;
            if (col < HC) {
                outL[(size_t)ng * HC + col] = acc[i][c];
            } else {
                float v = acc[i][c] + (add_bias ? bias[col - HC] : 0.0f);
                outR[(size_t)ng * HC + (col - HC)] = v;
            }
        }
    }
}

// ---------------- launch ----------------

extern "C" void kernel_launch(void* const* d_in, const int* in_sizes, int n_in,
                              void* d_out, int out_size, void* d_ws, size_t ws_size,
                              hipStream_t stream) {
    const float* x   = (const float*)d_in[0];
    const float* Wl1 = (const float*)d_in[1];
    const float* Wr1 = (const float*)d_in[2];
    const float* b1  = (const float*)d_in[3];
    const float* Wl2 = (const float*)d_in[4];
    const float* Wr2 = (const float*)d_in[5];
    const float* b2  = (const float*)d_in[6];
    const int* edge_src = (const int*)d_in[7];
    const int* edge_dst = (const int*)d_in[8];
    float* out = (float*)d_out;

    const int N = in_sizes[0] / 64;
    const int E = in_sizes[7];
    const int NBUCK = (N + (1 << BK_SHIFT) - 1) >> BK_SHIFT;   // 98
    const int NSTRIPS = (N + 15) >> SSHIFT;                    // 6250
    size_t bufC_bytes = (size_t)N * 64 * 4;
    int cap = E / NBUCK + E / (2 * NBUCK) + 1024;              // mean + 50% + slack
    int cap_max = (int)(bufC_bytes / ((size_t)NBUCK * 4));
    if (cap > cap_max) cap = cap_max;

    size_t off = 0;
    auto carve = [&](size_t bytes) -> void* {
        void* p = (char*)d_ws + off;
        off = (off + bytes + 255) & ~(size_t)255;
        return p;
    };
    int*          strip_off = (int*)carve((size_t)(NSTRIPS + 1) * 4);
    int*          bcursor   = (int*)carve((size_t)NBUCK * 4);
    float*        dis       = (float*)carve((size_t)N * 4);
    float*        cnt_inv   = (float*)carve((size_t)N * 4);
    unsigned int* csr       = (unsigned int*)carve((size_t)E * 4);
    float*        bufA      = (float*)carve((size_t)N * 64 * 4);
    float*        bufB      = (float*)carve((size_t)N * 64 * 4);
    float*        bufC      = (float*)carve(bufC_bytes);
    unsigned int* temp      = (unsigned int*)bufC;   // alias: dead before bufC written
    (void)ws_size;

    const int nb_prop = (NSTRIPS + 3) / 4;    // 1563 blocks, 4 strips each
    const int nb_gemm = (N + 63) / 64;

    // CSR build
    init_bcursor_kernel<<<(NBUCK + 255) / 256, 256, 0, stream>>>(bcursor, NBUCK, cap);
    partition_kernel<<<256, 256, 0, stream>>>(edge_src, edge_dst, bcursor, temp, E, NBUCK, cap);
    bucket_csr_kernel<<<NBUCK, 256, 0, stream>>>(temp, bcursor, dis, cnt_inv, csr, strip_off,
                                                 N, cap, NBUCK, E, NSTRIPS);

    // KProp x2: h = S (S x)
    propc2_kernel<64, true, 0, 1><<<nb_prop, 256, 0, stream>>>(x, bufA, strip_off, csr, dis, dis,
                                                               nullptr, nullptr, N, NSTRIPS);
    propc2_kernel<64, true, 0, 2><<<nb_prop, 256, 0, stream>>>(bufA, bufB, strip_off, csr, dis, dis,
                                                               nullptr, nullptr, N, NSTRIPS);
    // [t1|r1] = h @ [Wl1|Wr1]  (t1 -> bufA, r1 -> bufC)
    gemm_kernel<128, 8><<<nb_gemm, 256, 0, stream>>>(bufB, Wl1, Wr1, nullptr, bufA, bufC, N, 0);
    // h1 = selu(mean_agg(t1) + r1 + b1) -> bufB
    propc2_kernel<64, false, 1, 3><<<nb_prop, 256, 0, stream>>>(bufA, bufB, strip_off, csr, dis,
                                                                cnt_inv, bufC, b1, N, NSTRIPS);
    // [t2|r2+b2] = h1 @ [Wl2|Wr2]  (t2 -> bufA (N x 40), r2 -> bufC (N x 40))
    gemm_kernel<80, 5><<<nb_gemm, 256, 0, stream>>>(bufB, Wl2, Wr2, b2, bufA, bufC, N, 1);
    // out = softmax(mean_agg(t2) + r2)
    propc2_kernel<40, false, 2, 4><<<nb_prop, 256, 0, stream>>>(bufA, out, strip_off, csr, dis,
                                                                cnt_inv, bufC, nullptr, N, NSTRIPS);
}